// Round 1
// baseline (1435.113 us; speedup 1.0000x reference)
//
#include <hip/hip_runtime.h>
#include <math.h>

// Problem constants (fixed by the reference file)
#define NND 100000            // nodes
#define NED 1600000           // edges (before self-loops)
#define TOTE (NND + NED)      // edges + self-loops

// Workspace layout (bytes); total = 108.8 MB, must fit ws_size.
//   h     : N*128 f32 = 51,200,000
//   agg   : N*128 f32 = 51,200,000
//   a_src : N*4   f32 =  1,600,000
//   a_dst : N*4   f32 =  1,600,000
//   m     : N*4   f32 =  1,600,000
//   denom : N*4   f32 =  1,600,000
#define OFF_H     ((size_t)0)
#define OFF_AGG   ((size_t)51200000)
#define OFF_ASRC  ((size_t)102400000)
#define OFF_ADST  ((size_t)104000000)
#define OFF_M     ((size_t)105600000)
#define OFF_DEN   ((size_t)107200000)

__device__ __forceinline__ float leaky02(float v) { return v > 0.f ? v : 0.2f * v; }

// Two-sided float atomic max via int/uint monotone trick.
__device__ __forceinline__ void atomicMaxF(float* addr, float val) {
    if (val >= 0.f) atomicMax((int*)addr, __float_as_int(val));
    else            atomicMin((unsigned int*)addr, __float_as_uint(val));
}

// ---------------------------------------------------------------------------
// K1: h = x @ W  (N x 128 @ 128 x 128), fused a_src/a_dst head-dot epilogue.
// 128 threads/block, thread j owns W column j in registers; 32 rows/block.
// ---------------------------------------------------------------------------
__global__ __launch_bounds__(128)
void k_gemm1(const float* __restrict__ x, const float* __restrict__ W,
             const float* __restrict__ att_s, const float* __restrict__ att_d,
             float* __restrict__ h, float* __restrict__ a_src, float* __restrict__ a_dst)
{
    const int j = threadIdx.x;            // output channel 0..127
    const int row0 = blockIdx.x * 32;     // 3125 * 32 == 100000 exactly
    __shared__ float xs[32][128];

    float w[128];
#pragma unroll
    for (int k = 0; k < 128; ++k) w[k] = W[k * 128 + j];
    const float asj = att_s[j];
    const float adj = att_d[j];

#pragma unroll 8
    for (int r = 0; r < 32; ++r)
        xs[r][j] = x[(size_t)(row0 + r) * 128 + j];
    __syncthreads();

    for (int r = 0; r < 32; r += 4) {
        float a0 = 0.f, a1 = 0.f, a2 = 0.f, a3 = 0.f;
#pragma unroll
        for (int k = 0; k < 128; ++k) {
            const float wk = w[k];
            a0 += xs[r + 0][k] * wk;
            a1 += xs[r + 1][k] * wk;
            a2 += xs[r + 2][k] * wk;
            a3 += xs[r + 3][k] * wk;
        }
        const size_t base = (size_t)(row0 + r) * 128 + j;
        h[base]       = a0;
        h[base + 128] = a1;
        h[base + 256] = a2;
        h[base + 384] = a3;

        // a_src/a_dst: reduce h*att over the 32 channels of each head.
#pragma unroll
        for (int q = 0; q < 4; ++q) {
            const float hv = (q == 0) ? a0 : (q == 1) ? a1 : (q == 2) ? a2 : a3;
            float vs = hv * asj;
            float vd = hv * adj;
#pragma unroll
            for (int off = 16; off > 0; off >>= 1) {
                vs += __shfl_xor(vs, off, 32);
                vd += __shfl_xor(vd, off, 32);
            }
            if ((j & 31) == 0) {
                const int row = row0 + r + q;
                a_src[row * 4 + (j >> 5)] = vs;
                a_dst[row * 4 + (j >> 5)] = vd;
            }
        }
    }
}

// ---------------------------------------------------------------------------
// Init m to -1e30 (self-loops guarantee every node gets a finite max anyway).
// ---------------------------------------------------------------------------
__global__ void k_init_m(float* __restrict__ m) {
    const int i = blockIdx.x * blockDim.x + threadIdx.x;
    if (i < NND * 4) m[i] = -1e30f;
}

// ---------------------------------------------------------------------------
// Pass 1: segment max of leaky_relu(a_src[s]+a_dst[d]) into m[d][h].
// One thread per (edge or self-loop).
// ---------------------------------------------------------------------------
__global__ __launch_bounds__(256)
void k_pass1(const int* __restrict__ esrc, const int* __restrict__ edst,
             const float* __restrict__ a_src, const float* __restrict__ a_dst,
             float* __restrict__ m)
{
    const int e = blockIdx.x * 256 + threadIdx.x;
    if (e >= TOTE) return;
    int s, d;
    if (e < NED) { s = esrc[e]; d = edst[e]; } else { s = e - NED; d = s; }
    const float4 as = *(const float4*)(a_src + (size_t)s * 4);
    const float4 ad = *(const float4*)(a_dst + (size_t)d * 4);
    float* mp = m + (size_t)d * 4;
    atomicMaxF(mp + 0, leaky02(as.x + ad.x));
    atomicMaxF(mp + 1, leaky02(as.y + ad.y));
    atomicMaxF(mp + 2, leaky02(as.z + ad.z));
    atomicMaxF(mp + 3, leaky02(as.w + ad.w));
}

// ---------------------------------------------------------------------------
// Pass 2: denom[d][h] += exp(e - m[d][h])
// ---------------------------------------------------------------------------
__global__ __launch_bounds__(256)
void k_pass2(const int* __restrict__ esrc, const int* __restrict__ edst,
             const float* __restrict__ a_src, const float* __restrict__ a_dst,
             const float* __restrict__ m, float* __restrict__ denom)
{
    const int e = blockIdx.x * 256 + threadIdx.x;
    if (e >= TOTE) return;
    int s, d;
    if (e < NED) { s = esrc[e]; d = edst[e]; } else { s = e - NED; d = s; }
    const float4 as = *(const float4*)(a_src + (size_t)s * 4);
    const float4 ad = *(const float4*)(a_dst + (size_t)d * 4);
    const float4 mm = *(const float4*)(m + (size_t)d * 4);
    float* dp = denom + (size_t)d * 4;
    atomicAdd(dp + 0, __expf(leaky02(as.x + ad.x) - mm.x));
    atomicAdd(dp + 1, __expf(leaky02(as.y + ad.y) - mm.y));
    atomicAdd(dp + 2, __expf(leaky02(as.z + ad.z) - mm.z));
    atomicAdd(dp + 3, __expf(leaky02(as.w + ad.w) - mm.w));
}

// ---------------------------------------------------------------------------
// Pass 3: agg[d][c] += alpha[d<-s][head(c)] * h[s][c].
// One 64-lane wave per edge; lane covers channels lane and lane+64.
// ---------------------------------------------------------------------------
__global__ __launch_bounds__(256)
void k_pass3(const int* __restrict__ esrc, const int* __restrict__ edst,
             const float* __restrict__ a_src, const float* __restrict__ a_dst,
             const float* __restrict__ m, const float* __restrict__ denom,
             const float* __restrict__ h, float* __restrict__ agg)
{
    const int lane = threadIdx.x & 63;
    const int e = blockIdx.x * 4 + (threadIdx.x >> 6);
    if (e >= TOTE) return;
    int s, d;
    if (e < NED) { s = esrc[e]; d = edst[e]; } else { s = e - NED; d = s; }
    const float4 as = *(const float4*)(a_src + (size_t)s * 4);
    const float4 ad = *(const float4*)(a_dst + (size_t)d * 4);
    const float4 mm = *(const float4*)(m + (size_t)d * 4);
    const float4 dn = *(const float4*)(denom + (size_t)d * 4);
    const float al0 = __expf(leaky02(as.x + ad.x) - mm.x) / (dn.x + 1e-16f);
    const float al1 = __expf(leaky02(as.y + ad.y) - mm.y) / (dn.y + 1e-16f);
    const float al2 = __expf(leaky02(as.z + ad.z) - mm.z) / (dn.z + 1e-16f);
    const float al3 = __expf(leaky02(as.w + ad.w) - mm.w) / (dn.w + 1e-16f);
    // channels [0..31]=head0, [32..63]=head1, [64..95]=head2, [96..127]=head3
    const float aLo = (lane < 32) ? al0 : al1;
    const float aHi = (lane < 32) ? al2 : al3;
    const size_t hb = (size_t)s * 128 + lane;
    const size_t ab = (size_t)d * 128 + lane;
    atomicAdd(&agg[ab],      h[hb]      * aLo);
    atomicAdd(&agg[ab + 64], h[hb + 64] * aHi);
}

// ---------------------------------------------------------------------------
// K_out: out = relu(agg + bias) @ lin_w + lin_b   (N x 128 @ 128 x 64)
// 128 threads/block: thread = (half = t>>6, j = t&63); 16 rows/block.
// ---------------------------------------------------------------------------
__global__ __launch_bounds__(128)
void k_out(const float* __restrict__ agg, const float* __restrict__ bias,
           const float* __restrict__ lin_w, const float* __restrict__ lin_b,
           float* __restrict__ out)
{
    const int t = threadIdx.x;
    const int j = t & 63;
    const int half = t >> 6;
    const int row0 = blockIdx.x * 16;    // 6250 * 16 == 100000 exactly
    __shared__ float ys[16][128];

    float w[128];
#pragma unroll
    for (int k = 0; k < 128; ++k) w[k] = lin_w[(size_t)k * 64 + j];
    const float lb = lin_b[j];

    const float b0 = bias[t];
#pragma unroll 4
    for (int r = 0; r < 16; ++r) {
        const float v = agg[(size_t)(row0 + r) * 128 + t] + b0;
        ys[r][t] = v > 0.f ? v : 0.f;
    }
    __syncthreads();

#pragma unroll
    for (int g = 0; g < 2; ++g) {
        const int rb = g * 8 + half;    // rows rb, rb+2, rb+4, rb+6
        float a0 = 0.f, a1 = 0.f, a2 = 0.f, a3 = 0.f;
#pragma unroll
        for (int k = 0; k < 128; ++k) {
            const float wk = w[k];
            a0 += ys[rb + 0][k] * wk;
            a1 += ys[rb + 2][k] * wk;
            a2 += ys[rb + 4][k] * wk;
            a3 += ys[rb + 6][k] * wk;
        }
        out[(size_t)(row0 + rb + 0) * 64 + j] = a0 + lb;
        out[(size_t)(row0 + rb + 2) * 64 + j] = a1 + lb;
        out[(size_t)(row0 + rb + 4) * 64 + j] = a2 + lb;
        out[(size_t)(row0 + rb + 6) * 64 + j] = a3 + lb;
    }
}

extern "C" void kernel_launch(void* const* d_in, const int* in_sizes, int n_in,
                              void* d_out, int out_size, void* d_ws, size_t ws_size,
                              hipStream_t stream)
{
    const float* x     = (const float*)d_in[0];
    const int*   ei    = (const int*)  d_in[1];   // [2][E] int32
    const float* W     = (const float*)d_in[2];
    const float* att_s = (const float*)d_in[3];
    const float* att_d = (const float*)d_in[4];
    const float* bias  = (const float*)d_in[5];
    const float* lin_w = (const float*)d_in[6];
    const float* lin_b = (const float*)d_in[7];
    float* out = (float*)d_out;

    const int* esrc = ei;        // edge_index[0] = message source
    const int* edst = ei + NED;  // edge_index[1] = message target

    char* ws = (char*)d_ws;
    float* h     = (float*)(ws + OFF_H);
    float* agg   = (float*)(ws + OFF_AGG);
    float* a_src = (float*)(ws + OFF_ASRC);
    float* a_dst = (float*)(ws + OFF_ADST);
    float* m     = (float*)(ws + OFF_M);
    float* denom = (float*)(ws + OFF_DEN);

    hipMemsetAsync(agg,   0, (size_t)NND * 128 * sizeof(float), stream);
    hipMemsetAsync(denom, 0, (size_t)NND * 4   * sizeof(float), stream);
    k_init_m<<<(NND * 4 + 255) / 256, 256, 0, stream>>>(m);

    k_gemm1<<<NND / 32, 128, 0, stream>>>(x, W, att_s, att_d, h, a_src, a_dst);
    k_pass1<<<(TOTE + 255) / 256, 256, 0, stream>>>(esrc, edst, a_src, a_dst, m);
    k_pass2<<<(TOTE + 255) / 256, 256, 0, stream>>>(esrc, edst, a_src, a_dst, m, denom);
    k_pass3<<<(TOTE + 3) / 4, 256, 0, stream>>>(esrc, edst, a_src, a_dst, m, denom, h, agg);
    k_out<<<NND / 16, 128, 0, stream>>>(agg, bias, lin_w, lin_b, out);
}

// Round 2
// 617.355 us; speedup vs baseline: 2.3246x; 2.3246x over previous
//
#include <hip/hip_runtime.h>
#include <math.h>

// Problem constants (fixed by the reference file)
#define NND 100000            // nodes
#define NED 1600000           // edges (before self-loops)
#define TOTE (NND + NED)      // edges + self-loops

// Workspace layout (bytes); total = 113.2 MB.
//   h      : N*128 f32 = 51,200,000
//   agg    : N*128 f32 = 51,200,000
//   a_src  : N*4   f32 =  1,600,000
//   a_dst  : N*4   f32 =  1,600,000
//   offs   : (N+1) i32 =    400,004 (padded to 400,016)
//   counts : N     i32 =    400,000 (doubles as scatter cursor)
//   ssrt   : TOTE  i32 =  6,800,000 (dst-sorted source ids)
#define OFF_H     ((size_t)0)
#define OFF_AGG   ((size_t)51200000)
#define OFF_ASRC  ((size_t)102400000)
#define OFF_ADST  ((size_t)104000000)
#define OFF_OFFS  ((size_t)105600000)
#define OFF_CNT   ((size_t)106000016)
#define OFF_SRT   ((size_t)106400016)

__device__ __forceinline__ float leaky02(float v) { return v > 0.f ? v : 0.2f * v; }

// ---------------------------------------------------------------------------
// CSR build: counts=1 (self-loop) -> histogram edges by dst -> scan -> fill
// self-loop at segment head -> scatter edge sources.
// ---------------------------------------------------------------------------
__global__ __launch_bounds__(256)
void k_count_init(int* __restrict__ counts) {
    const int i = blockIdx.x * 256 + threadIdx.x;
    if (i < NND) counts[i] = 1;
}

__global__ __launch_bounds__(256)
void k_hist(const int* __restrict__ edst, int* __restrict__ counts) {
    const int e = blockIdx.x * 256 + threadIdx.x;
    if (e < NED) atomicAdd(&counts[edst[e]], 1);
}

// Single-block scan: off[0]=0, off[i+1]=sum(counts[0..i]).
__global__ __launch_bounds__(1024)
void k_scan(const int* __restrict__ counts, int* __restrict__ off) {
    __shared__ int part[1024];
    const int t = threadIdx.x;
    const int chunk = (NND + 1023) / 1024;           // 98
    const int lo = t * chunk;
    const int hi = min(NND, lo + chunk);
    int s = 0;
    for (int i = lo; i < hi; ++i) s += counts[i];
    part[t] = s;
    __syncthreads();
    for (int d = 1; d < 1024; d <<= 1) {
        int v = (t >= d) ? part[t - d] : 0;
        __syncthreads();
        part[t] += v;
        __syncthreads();
    }
    int run = (t == 0) ? 0 : part[t - 1];
    if (t == 0) off[0] = 0;
    for (int i = lo; i < hi; ++i) { run += counts[i]; off[i + 1] = run; }
}

__global__ __launch_bounds__(256)
void k_fill_self(const int* __restrict__ off, int* __restrict__ ssrt,
                 int* __restrict__ counts) {
    const int d = blockIdx.x * 256 + threadIdx.x;
    if (d < NND) { ssrt[off[d]] = d; counts[d] = 1; }
}

__global__ __launch_bounds__(256)
void k_scatter(const int* __restrict__ esrc, const int* __restrict__ edst,
               const int* __restrict__ off, int* __restrict__ counts,
               int* __restrict__ ssrt) {
    const int e = blockIdx.x * 256 + threadIdx.x;
    if (e >= NED) return;
    const int d = edst[e];
    const int pos = off[d] + atomicAdd(&counts[d], 1);
    ssrt[pos] = esrc[e];
}

// ---------------------------------------------------------------------------
// K1: h = x @ W  (N x 128 @ 128 x 128), fused a_src/a_dst head-dot epilogue.
// ---------------------------------------------------------------------------
__global__ __launch_bounds__(128)
void k_gemm1(const float* __restrict__ x, const float* __restrict__ W,
             const float* __restrict__ att_s, const float* __restrict__ att_d,
             float* __restrict__ h, float* __restrict__ a_src, float* __restrict__ a_dst)
{
    const int j = threadIdx.x;            // output channel 0..127
    const int row0 = blockIdx.x * 32;     // 3125 * 32 == 100000 exactly
    __shared__ float xs[32][128];

    float w[128];
#pragma unroll
    for (int k = 0; k < 128; ++k) w[k] = W[k * 128 + j];
    const float asj = att_s[j];
    const float adj = att_d[j];

#pragma unroll 8
    for (int r = 0; r < 32; ++r)
        xs[r][j] = x[(size_t)(row0 + r) * 128 + j];
    __syncthreads();

    for (int r = 0; r < 32; r += 4) {
        float a0 = 0.f, a1 = 0.f, a2 = 0.f, a3 = 0.f;
#pragma unroll
        for (int k = 0; k < 128; ++k) {
            const float wk = w[k];
            a0 += xs[r + 0][k] * wk;
            a1 += xs[r + 1][k] * wk;
            a2 += xs[r + 2][k] * wk;
            a3 += xs[r + 3][k] * wk;
        }
        const size_t base = (size_t)(row0 + r) * 128 + j;
        h[base]       = a0;
        h[base + 128] = a1;
        h[base + 256] = a2;
        h[base + 384] = a3;

#pragma unroll
        for (int q = 0; q < 4; ++q) {
            const float hv = (q == 0) ? a0 : (q == 1) ? a1 : (q == 2) ? a2 : a3;
            float vs = hv * asj;
            float vd = hv * adj;
#pragma unroll
            for (int off = 16; off > 0; off >>= 1) {
                vs += __shfl_xor(vs, off, 32);
                vd += __shfl_xor(vd, off, 32);
            }
            if ((j & 31) == 0) {
                const int row = row0 + r + q;
                a_src[row * 4 + (j >> 5)] = vs;
                a_dst[row * 4 + (j >> 5)] = vd;
            }
        }
    }
}

// ---------------------------------------------------------------------------
// Fused segment softmax + aggregation. One 64-lane wave per destination node.
// Lane k owns incoming edge k (deg<=64 common case: Poisson(16)+1), holds its
// source id + 4 head logits in registers. Wave shfl reductions for max/sum.
// Aggregation: sequential loop over segment edges; per edge the wave gathers
// the full 512B h[src] row (float2/lane), alpha broadcast via shfl.
// ---------------------------------------------------------------------------
__global__ __launch_bounds__(256)
void k_fused(const int* __restrict__ off, const int* __restrict__ ssrt,
             const float* __restrict__ a_src, const float* __restrict__ a_dst,
             const float* __restrict__ h, float* __restrict__ agg)
{
    const int lane = threadIdx.x & 63;
    const int d = blockIdx.x * 4 + (threadIdx.x >> 6);
    if (d >= NND) return;
    const int beg = off[d];
    const int deg = off[d + 1] - beg;
    const float4 ad = *(const float4*)(a_dst + (size_t)d * 4);

    // chunk 0: lane's own edge
    int mysrc = d;
    float4 e4 = make_float4(-1e30f, -1e30f, -1e30f, -1e30f);
    if (lane < deg) {
        mysrc = ssrt[beg + lane];
        const float4 as = *(const float4*)(a_src + (size_t)mysrc * 4);
        e4.x = leaky02(as.x + ad.x);
        e4.y = leaky02(as.y + ad.y);
        e4.z = leaky02(as.z + ad.z);
        e4.w = leaky02(as.w + ad.w);
    }
    // segment max
    float4 mx = e4;
    for (int base = 64; base < deg; base += 64) {
        if (base + lane < deg) {
            const int s = ssrt[beg + base + lane];
            const float4 as = *(const float4*)(a_src + (size_t)s * 4);
            mx.x = fmaxf(mx.x, leaky02(as.x + ad.x));
            mx.y = fmaxf(mx.y, leaky02(as.y + ad.y));
            mx.z = fmaxf(mx.z, leaky02(as.z + ad.z));
            mx.w = fmaxf(mx.w, leaky02(as.w + ad.w));
        }
    }
#pragma unroll
    for (int o = 32; o > 0; o >>= 1) {
        mx.x = fmaxf(mx.x, __shfl_xor(mx.x, o, 64));
        mx.y = fmaxf(mx.y, __shfl_xor(mx.y, o, 64));
        mx.z = fmaxf(mx.z, __shfl_xor(mx.z, o, 64));
        mx.w = fmaxf(mx.w, __shfl_xor(mx.w, o, 64));
    }
    // exp + segment sum
    float4 ex = make_float4(0.f, 0.f, 0.f, 0.f);
    if (lane < deg) {
        ex.x = __expf(e4.x - mx.x);
        ex.y = __expf(e4.y - mx.y);
        ex.z = __expf(e4.z - mx.z);
        ex.w = __expf(e4.w - mx.w);
    }
    float4 sm = ex;
    for (int base = 64; base < deg; base += 64) {
        if (base + lane < deg) {
            const int s = ssrt[beg + base + lane];
            const float4 as = *(const float4*)(a_src + (size_t)s * 4);
            sm.x += __expf(leaky02(as.x + ad.x) - mx.x);
            sm.y += __expf(leaky02(as.y + ad.y) - mx.y);
            sm.z += __expf(leaky02(as.z + ad.z) - mx.z);
            sm.w += __expf(leaky02(as.w + ad.w) - mx.w);
        }
    }
#pragma unroll
    for (int o = 32; o > 0; o >>= 1) {
        sm.x += __shfl_xor(sm.x, o, 64);
        sm.y += __shfl_xor(sm.y, o, 64);
        sm.z += __shfl_xor(sm.z, o, 64);
        sm.w += __shfl_xor(sm.w, o, 64);
    }
    const float4 inv = make_float4(1.f / (sm.x + 1e-16f), 1.f / (sm.y + 1e-16f),
                                   1.f / (sm.z + 1e-16f), 1.f / (sm.w + 1e-16f));
    float4 al = make_float4(ex.x * inv.x, ex.y * inv.y, ex.z * inv.z, ex.w * inv.w);

    // aggregation: lane covers channels (2*lane, 2*lane+1); head = lane>>4
    const int hsel = lane >> 4;
    float2 acc = make_float2(0.f, 0.f);
    {
        const int cnt = min(deg, 64);
        for (int k = 0; k < cnt; ++k) {
            const int s = __shfl(mysrc, k, 64);
            const float ax = __shfl(al.x, k, 64);
            const float ay = __shfl(al.y, k, 64);
            const float az = __shfl(al.z, k, 64);
            const float aw = __shfl(al.w, k, 64);
            const float a = (hsel == 0) ? ax : (hsel == 1) ? ay : (hsel == 2) ? az : aw;
            const float2 hv = *(const float2*)(h + (size_t)s * 128 + 2 * lane);
            acc.x += hv.x * a;
            acc.y += hv.y * a;
        }
    }
    for (int base = 64; base < deg; base += 64) {
        const int cnt = min(64, deg - base);
        int s2 = d;
        float4 al2 = make_float4(0.f, 0.f, 0.f, 0.f);
        if (lane < cnt) {
            s2 = ssrt[beg + base + lane];
            const float4 as = *(const float4*)(a_src + (size_t)s2 * 4);
            al2.x = __expf(leaky02(as.x + ad.x) - mx.x) * inv.x;
            al2.y = __expf(leaky02(as.y + ad.y) - mx.y) * inv.y;
            al2.z = __expf(leaky02(as.z + ad.z) - mx.z) * inv.z;
            al2.w = __expf(leaky02(as.w + ad.w) - mx.w) * inv.w;
        }
        for (int k = 0; k < cnt; ++k) {
            const int s = __shfl(s2, k, 64);
            const float ax = __shfl(al2.x, k, 64);
            const float ay = __shfl(al2.y, k, 64);
            const float az = __shfl(al2.z, k, 64);
            const float aw = __shfl(al2.w, k, 64);
            const float a = (hsel == 0) ? ax : (hsel == 1) ? ay : (hsel == 2) ? az : aw;
            const float2 hv = *(const float2*)(h + (size_t)s * 128 + 2 * lane);
            acc.x += hv.x * a;
            acc.y += hv.y * a;
        }
    }
    *(float2*)(agg + (size_t)d * 128 + 2 * lane) = acc;
}

// ---------------------------------------------------------------------------
// K_out: out = relu(agg + bias) @ lin_w + lin_b   (N x 128 @ 128 x 64)
// ---------------------------------------------------------------------------
__global__ __launch_bounds__(128)
void k_out(const float* __restrict__ agg, const float* __restrict__ bias,
           const float* __restrict__ lin_w, const float* __restrict__ lin_b,
           float* __restrict__ out)
{
    const int t = threadIdx.x;
    const int j = t & 63;
    const int half = t >> 6;
    const int row0 = blockIdx.x * 16;    // 6250 * 16 == 100000 exactly
    __shared__ float ys[16][128];

    float w[128];
#pragma unroll
    for (int k = 0; k < 128; ++k) w[k] = lin_w[(size_t)k * 64 + j];
    const float lb = lin_b[j];

    const float b0 = bias[t];
#pragma unroll 4
    for (int r = 0; r < 16; ++r) {
        const float v = agg[(size_t)(row0 + r) * 128 + t] + b0;
        ys[r][t] = v > 0.f ? v : 0.f;
    }
    __syncthreads();

#pragma unroll
    for (int g = 0; g < 2; ++g) {
        const int rb = g * 8 + half;
        float a0 = 0.f, a1 = 0.f, a2 = 0.f, a3 = 0.f;
#pragma unroll
        for (int k = 0; k < 128; ++k) {
            const float wk = w[k];
            a0 += ys[rb + 0][k] * wk;
            a1 += ys[rb + 2][k] * wk;
            a2 += ys[rb + 4][k] * wk;
            a3 += ys[rb + 6][k] * wk;
        }
        out[(size_t)(row0 + rb + 0) * 64 + j] = a0 + lb;
        out[(size_t)(row0 + rb + 2) * 64 + j] = a1 + lb;
        out[(size_t)(row0 + rb + 4) * 64 + j] = a2 + lb;
        out[(size_t)(row0 + rb + 6) * 64 + j] = a3 + lb;
    }
}

extern "C" void kernel_launch(void* const* d_in, const int* in_sizes, int n_in,
                              void* d_out, int out_size, void* d_ws, size_t ws_size,
                              hipStream_t stream)
{
    const float* x     = (const float*)d_in[0];
    const int*   ei    = (const int*)  d_in[1];   // [2][E] int32
    const float* W     = (const float*)d_in[2];
    const float* att_s = (const float*)d_in[3];
    const float* att_d = (const float*)d_in[4];
    const float* bias  = (const float*)d_in[5];
    const float* lin_w = (const float*)d_in[6];
    const float* lin_b = (const float*)d_in[7];
    float* out = (float*)d_out;

    const int* esrc = ei;        // edge_index[0] = message source
    const int* edst = ei + NED;  // edge_index[1] = message target

    char* ws = (char*)d_ws;
    float* h     = (float*)(ws + OFF_H);
    float* agg   = (float*)(ws + OFF_AGG);
    float* a_src = (float*)(ws + OFF_ASRC);
    float* a_dst = (float*)(ws + OFF_ADST);
    int*   offs  = (int*)  (ws + OFF_OFFS);
    int*   cnts  = (int*)  (ws + OFF_CNT);
    int*   ssrt  = (int*)  (ws + OFF_SRT);

    // CSR build (dst-sorted edge list, self-loop at each segment head)
    k_count_init<<<(NND + 255) / 256, 256, 0, stream>>>(cnts);
    k_hist<<<(NED + 255) / 256, 256, 0, stream>>>(edst, cnts);
    k_scan<<<1, 1024, 0, stream>>>(cnts, offs);
    k_fill_self<<<(NND + 255) / 256, 256, 0, stream>>>(offs, ssrt, cnts);
    k_scatter<<<(NED + 255) / 256, 256, 0, stream>>>(esrc, edst, offs, cnts, ssrt);

    // feature transform + attention logits
    k_gemm1<<<NND / 32, 128, 0, stream>>>(x, W, att_s, att_d, h, a_src, a_dst);

    // fused segment softmax + aggregation (no atomics)
    k_fused<<<(NND + 3) / 4, 256, 0, stream>>>(offs, ssrt, a_src, a_dst, h, agg);

    // output projection
    k_out<<<NND / 16, 128, 0, stream>>>(agg, bias, lin_w, lin_b, out);
}

// Round 3
// 471.615 us; speedup vs baseline: 3.0430x; 1.3090x over previous
//
#include <hip/hip_runtime.h>
#include <math.h>

// Problem constants (fixed by the reference file)
#define NND 100000            // nodes
#define NED 1600000           // edges (before self-loops)
#define TOTE (NND + NED)      // edges + self-loops

#define SCAN_BS 256
#define SCAN_NB ((NND + SCAN_BS - 1) / SCAN_BS)   // 391

// Workspace layout (bytes)
//   h      : N*128 f32 = 51,200,000
//   agg    : N*128 f32 = 51,200,000
//   a_src  : N*4   f32 =  1,600,000
//   a_dst  : N*4   f32 =  1,600,000
//   offs   : (N+1) i32 =    400,004 (padded to 400,016)
//   counts : N     i32 =    400,000 (doubles as scatter cursor)
//   ssrt   : TOTE  i32 =  6,800,000 (dst-sorted source ids)
//   bsum   : NB    i32 (block partial sums for scan)
//   bpref  : NB    i32 (exclusive block prefixes)
#define OFF_H     ((size_t)0)
#define OFF_AGG   ((size_t)51200000)
#define OFF_ASRC  ((size_t)102400000)
#define OFF_ADST  ((size_t)104000000)
#define OFF_OFFS  ((size_t)105600000)
#define OFF_CNT   ((size_t)106000016)
#define OFF_SRT   ((size_t)106400016)
#define OFF_BSUM  ((size_t)113200016)
#define OFF_BPREF ((size_t)113204016)

__device__ __forceinline__ float leaky02(float v) { return v > 0.f ? v : 0.2f * v; }

// ---------------------------------------------------------------------------
// CSR build: counts=1 (self-loop) -> histogram by dst -> hierarchical scan ->
// fill self-loop at segment head -> scatter edge sources.
// ---------------------------------------------------------------------------
__global__ __launch_bounds__(256)
void k_count_init(int* __restrict__ counts) {
    const int i = blockIdx.x * 256 + threadIdx.x;
    if (i < NND) counts[i] = 1;
}

__global__ __launch_bounds__(256)
void k_hist(const int* __restrict__ edst, int* __restrict__ counts) {
    const int e = blockIdx.x * 256 + threadIdx.x;
    if (e < NED) atomicAdd(&counts[edst[e]], 1);
}

// Scan stage 1: per-block sums of counts.
__global__ __launch_bounds__(SCAN_BS)
void k_scan_partial(const int* __restrict__ counts, int* __restrict__ bsum) {
    __shared__ int s[SCAN_BS];
    const int t = threadIdx.x;
    const int i = blockIdx.x * SCAN_BS + t;
    s[t] = (i < NND) ? counts[i] : 0;
    __syncthreads();
#pragma unroll
    for (int d = SCAN_BS / 2; d > 0; d >>= 1) {
        if (t < d) s[t] += s[t + d];
        __syncthreads();
    }
    if (t == 0) bsum[blockIdx.x] = s[0];
}

// Scan stage 2: one block scans the 391 block sums -> exclusive prefixes.
__global__ __launch_bounds__(512)
void k_scan_bsums(const int* __restrict__ bsum, int* __restrict__ bpref) {
    __shared__ int s[512];
    const int t = threadIdx.x;
    const int v0 = (t < SCAN_NB) ? bsum[t] : 0;
    s[t] = v0;
    __syncthreads();
#pragma unroll
    for (int d = 1; d < 512; d <<= 1) {
        int v = (t >= d) ? s[t - d] : 0;
        __syncthreads();
        s[t] += v;
        __syncthreads();
    }
    if (t < SCAN_NB) bpref[t] = s[t] - v0;   // exclusive
}

// Scan stage 3: per-block inclusive scan + block base -> off[i+1]; off[0]=0.
__global__ __launch_bounds__(SCAN_BS)
void k_scan_final(const int* __restrict__ counts, const int* __restrict__ bpref,
                  int* __restrict__ off) {
    __shared__ int s[SCAN_BS];
    const int t = threadIdx.x;
    const int i = blockIdx.x * SCAN_BS + t;
    const int v0 = (i < NND) ? counts[i] : 0;
    s[t] = v0;
    __syncthreads();
#pragma unroll
    for (int d = 1; d < SCAN_BS; d <<= 1) {
        int v = (t >= d) ? s[t - d] : 0;
        __syncthreads();
        s[t] += v;
        __syncthreads();
    }
    if (i < NND) off[i + 1] = bpref[blockIdx.x] + s[t];
    if (i == 0) off[0] = 0;
}

__global__ __launch_bounds__(256)
void k_fill_self(const int* __restrict__ off, int* __restrict__ ssrt,
                 int* __restrict__ counts) {
    const int d = blockIdx.x * 256 + threadIdx.x;
    if (d < NND) { ssrt[off[d]] = d; counts[d] = 1; }
}

__global__ __launch_bounds__(256)
void k_scatter(const int* __restrict__ esrc, const int* __restrict__ edst,
               const int* __restrict__ off, int* __restrict__ counts,
               int* __restrict__ ssrt) {
    const int e = blockIdx.x * 256 + threadIdx.x;
    if (e >= NED) return;
    const int d = edst[e];
    const int pos = off[d] + atomicAdd(&counts[d], 1);
    ssrt[pos] = esrc[e];
}

// ---------------------------------------------------------------------------
// K1: h = x @ W  (N x 128 @ 128 x 128), fused a_src/a_dst head-dot epilogue.
// 128 threads/block, thread j owns W column j in registers; 32 rows/block,
// 8-row ILP.
// ---------------------------------------------------------------------------
__global__ __launch_bounds__(128)
void k_gemm1(const float* __restrict__ x, const float* __restrict__ W,
             const float* __restrict__ att_s, const float* __restrict__ att_d,
             float* __restrict__ h, float* __restrict__ a_src, float* __restrict__ a_dst)
{
    const int j = threadIdx.x;            // output channel 0..127
    const int row0 = blockIdx.x * 32;     // 3125 * 32 == 100000 exactly
    __shared__ float xs[32][128];

    float w[128];
#pragma unroll
    for (int k = 0; k < 128; ++k) w[k] = W[k * 128 + j];
    const float asj = att_s[j];
    const float adj = att_d[j];

#pragma unroll 8
    for (int r = 0; r < 32; ++r)
        xs[r][j] = x[(size_t)(row0 + r) * 128 + j];
    __syncthreads();

    for (int r = 0; r < 32; r += 8) {
        float acc[8];
#pragma unroll
        for (int q = 0; q < 8; ++q) acc[q] = 0.f;
#pragma unroll
        for (int k = 0; k < 128; ++k) {
            const float wk = w[k];
#pragma unroll
            for (int q = 0; q < 8; ++q)
                acc[q] += xs[r + q][k] * wk;
        }
#pragma unroll
        for (int q = 0; q < 8; ++q)
            h[(size_t)(row0 + r + q) * 128 + j] = acc[q];

#pragma unroll
        for (int q = 0; q < 8; ++q) {
            float vs = acc[q] * asj;
            float vd = acc[q] * adj;
#pragma unroll
            for (int off = 16; off > 0; off >>= 1) {
                vs += __shfl_xor(vs, off, 32);
                vd += __shfl_xor(vd, off, 32);
            }
            if ((j & 31) == 0) {
                const int row = row0 + r + q;
                a_src[row * 4 + (j >> 5)] = vs;
                a_dst[row * 4 + (j >> 5)] = vd;
            }
        }
    }
}

// ---------------------------------------------------------------------------
// Fused segment softmax + aggregation. One 64-lane wave per destination node.
// ---------------------------------------------------------------------------
__global__ __launch_bounds__(256)
void k_fused(const int* __restrict__ off, const int* __restrict__ ssrt,
             const float* __restrict__ a_src, const float* __restrict__ a_dst,
             const float* __restrict__ h, float* __restrict__ agg)
{
    const int lane = threadIdx.x & 63;
    const int d = blockIdx.x * 4 + (threadIdx.x >> 6);
    if (d >= NND) return;
    const int beg = off[d];
    const int deg = off[d + 1] - beg;
    const float4 ad = *(const float4*)(a_dst + (size_t)d * 4);

    int mysrc = d;
    float4 e4 = make_float4(-1e30f, -1e30f, -1e30f, -1e30f);
    if (lane < deg) {
        mysrc = ssrt[beg + lane];
        const float4 as = *(const float4*)(a_src + (size_t)mysrc * 4);
        e4.x = leaky02(as.x + ad.x);
        e4.y = leaky02(as.y + ad.y);
        e4.z = leaky02(as.z + ad.z);
        e4.w = leaky02(as.w + ad.w);
    }
    float4 mx = e4;
    for (int base = 64; base < deg; base += 64) {
        if (base + lane < deg) {
            const int s = ssrt[beg + base + lane];
            const float4 as = *(const float4*)(a_src + (size_t)s * 4);
            mx.x = fmaxf(mx.x, leaky02(as.x + ad.x));
            mx.y = fmaxf(mx.y, leaky02(as.y + ad.y));
            mx.z = fmaxf(mx.z, leaky02(as.z + ad.z));
            mx.w = fmaxf(mx.w, leaky02(as.w + ad.w));
        }
    }
#pragma unroll
    for (int o = 32; o > 0; o >>= 1) {
        mx.x = fmaxf(mx.x, __shfl_xor(mx.x, o, 64));
        mx.y = fmaxf(mx.y, __shfl_xor(mx.y, o, 64));
        mx.z = fmaxf(mx.z, __shfl_xor(mx.z, o, 64));
        mx.w = fmaxf(mx.w, __shfl_xor(mx.w, o, 64));
    }
    float4 ex = make_float4(0.f, 0.f, 0.f, 0.f);
    if (lane < deg) {
        ex.x = __expf(e4.x - mx.x);
        ex.y = __expf(e4.y - mx.y);
        ex.z = __expf(e4.z - mx.z);
        ex.w = __expf(e4.w - mx.w);
    }
    float4 sm = ex;
    for (int base = 64; base < deg; base += 64) {
        if (base + lane < deg) {
            const int s = ssrt[beg + base + lane];
            const float4 as = *(const float4*)(a_src + (size_t)s * 4);
            sm.x += __expf(leaky02(as.x + ad.x) - mx.x);
            sm.y += __expf(leaky02(as.y + ad.y) - mx.y);
            sm.z += __expf(leaky02(as.z + ad.z) - mx.z);
            sm.w += __expf(leaky02(as.w + ad.w) - mx.w);
        }
    }
#pragma unroll
    for (int o = 32; o > 0; o >>= 1) {
        sm.x += __shfl_xor(sm.x, o, 64);
        sm.y += __shfl_xor(sm.y, o, 64);
        sm.z += __shfl_xor(sm.z, o, 64);
        sm.w += __shfl_xor(sm.w, o, 64);
    }
    const float4 inv = make_float4(1.f / (sm.x + 1e-16f), 1.f / (sm.y + 1e-16f),
                                   1.f / (sm.z + 1e-16f), 1.f / (sm.w + 1e-16f));
    float4 al = make_float4(ex.x * inv.x, ex.y * inv.y, ex.z * inv.z, ex.w * inv.w);

    const int hsel = lane >> 4;
    float2 acc = make_float2(0.f, 0.f);
    {
        const int cnt = min(deg, 64);
        for (int k = 0; k < cnt; ++k) {
            const int s = __shfl(mysrc, k, 64);
            const float ax = __shfl(al.x, k, 64);
            const float ay = __shfl(al.y, k, 64);
            const float az = __shfl(al.z, k, 64);
            const float aw = __shfl(al.w, k, 64);
            const float a = (hsel == 0) ? ax : (hsel == 1) ? ay : (hsel == 2) ? az : aw;
            const float2 hv = *(const float2*)(h + (size_t)s * 128 + 2 * lane);
            acc.x += hv.x * a;
            acc.y += hv.y * a;
        }
    }
    for (int base = 64; base < deg; base += 64) {
        const int cnt = min(64, deg - base);
        int s2 = d;
        float4 al2 = make_float4(0.f, 0.f, 0.f, 0.f);
        if (lane < cnt) {
            s2 = ssrt[beg + base + lane];
            const float4 as = *(const float4*)(a_src + (size_t)s2 * 4);
            al2.x = __expf(leaky02(as.x + ad.x) - mx.x) * inv.x;
            al2.y = __expf(leaky02(as.y + ad.y) - mx.y) * inv.y;
            al2.z = __expf(leaky02(as.z + ad.z) - mx.z) * inv.z;
            al2.w = __expf(leaky02(as.w + ad.w) - mx.w) * inv.w;
        }
        for (int k = 0; k < cnt; ++k) {
            const int s = __shfl(s2, k, 64);
            const float ax = __shfl(al2.x, k, 64);
            const float ay = __shfl(al2.y, k, 64);
            const float az = __shfl(al2.z, k, 64);
            const float aw = __shfl(al2.w, k, 64);
            const float a = (hsel == 0) ? ax : (hsel == 1) ? ay : (hsel == 2) ? az : aw;
            const float2 hv = *(const float2*)(h + (size_t)s * 128 + 2 * lane);
            acc.x += hv.x * a;
            acc.y += hv.y * a;
        }
    }
    *(float2*)(agg + (size_t)d * 128 + 2 * lane) = acc;
}

// ---------------------------------------------------------------------------
// K_out: out = relu(agg + bias) @ lin_w + lin_b   (N x 128 @ 128 x 64)
// ---------------------------------------------------------------------------
__global__ __launch_bounds__(128)
void k_out(const float* __restrict__ agg, const float* __restrict__ bias,
           const float* __restrict__ lin_w, const float* __restrict__ lin_b,
           float* __restrict__ out)
{
    const int t = threadIdx.x;
    const int j = t & 63;
    const int half = t >> 6;
    const int row0 = blockIdx.x * 16;    // 6250 * 16 == 100000 exactly
    __shared__ float ys[16][128];

    float w[128];
#pragma unroll
    for (int k = 0; k < 128; ++k) w[k] = lin_w[(size_t)k * 64 + j];
    const float lb = lin_b[j];

    const float b0 = bias[t];
#pragma unroll 4
    for (int r = 0; r < 16; ++r) {
        const float v = agg[(size_t)(row0 + r) * 128 + t] + b0;
        ys[r][t] = v > 0.f ? v : 0.f;
    }
    __syncthreads();

#pragma unroll
    for (int g = 0; g < 2; ++g) {
        const int rb = g * 8 + half;
        float a0 = 0.f, a1 = 0.f, a2 = 0.f, a3 = 0.f;
#pragma unroll
        for (int k = 0; k < 128; ++k) {
            const float wk = w[k];
            a0 += ys[rb + 0][k] * wk;
            a1 += ys[rb + 2][k] * wk;
            a2 += ys[rb + 4][k] * wk;
            a3 += ys[rb + 6][k] * wk;
        }
        out[(size_t)(row0 + rb + 0) * 64 + j] = a0 + lb;
        out[(size_t)(row0 + rb + 2) * 64 + j] = a1 + lb;
        out[(size_t)(row0 + rb + 4) * 64 + j] = a2 + lb;
        out[(size_t)(row0 + rb + 6) * 64 + j] = a3 + lb;
    }
}

extern "C" void kernel_launch(void* const* d_in, const int* in_sizes, int n_in,
                              void* d_out, int out_size, void* d_ws, size_t ws_size,
                              hipStream_t stream)
{
    const float* x     = (const float*)d_in[0];
    const int*   ei    = (const int*)  d_in[1];   // [2][E] int32
    const float* W     = (const float*)d_in[2];
    const float* att_s = (const float*)d_in[3];
    const float* att_d = (const float*)d_in[4];
    const float* bias  = (const float*)d_in[5];
    const float* lin_w = (const float*)d_in[6];
    const float* lin_b = (const float*)d_in[7];
    float* out = (float*)d_out;

    const int* esrc = ei;        // edge_index[0] = message source
    const int* edst = ei + NED;  // edge_index[1] = message target

    char* ws = (char*)d_ws;
    float* h     = (float*)(ws + OFF_H);
    float* agg   = (float*)(ws + OFF_AGG);
    float* a_src = (float*)(ws + OFF_ASRC);
    float* a_dst = (float*)(ws + OFF_ADST);
    int*   offs  = (int*)  (ws + OFF_OFFS);
    int*   cnts  = (int*)  (ws + OFF_CNT);
    int*   ssrt  = (int*)  (ws + OFF_SRT);
    int*   bsum  = (int*)  (ws + OFF_BSUM);
    int*   bpref = (int*)  (ws + OFF_BPREF);

    // CSR build (dst-sorted edge list, self-loop at each segment head)
    k_count_init<<<(NND + 255) / 256, 256, 0, stream>>>(cnts);
    k_hist<<<(NED + 255) / 256, 256, 0, stream>>>(edst, cnts);
    k_scan_partial<<<SCAN_NB, SCAN_BS, 0, stream>>>(cnts, bsum);
    k_scan_bsums<<<1, 512, 0, stream>>>(bsum, bpref);
    k_scan_final<<<SCAN_NB, SCAN_BS, 0, stream>>>(cnts, bpref, offs);
    k_fill_self<<<(NND + 255) / 256, 256, 0, stream>>>(offs, ssrt, cnts);
    k_scatter<<<(NED + 255) / 256, 256, 0, stream>>>(esrc, edst, offs, cnts, ssrt);

    // feature transform + attention logits
    k_gemm1<<<NND / 32, 128, 0, stream>>>(x, W, att_s, att_d, h, a_src, a_dst);

    // fused segment softmax + aggregation (no atomics)
    k_fused<<<(NND + 3) / 4, 256, 0, stream>>>(offs, ssrt, a_src, a_dst, h, agg);

    // output projection
    k_out<<<NND / 16, 128, 0, stream>>>(agg, bias, lin_w, lin_b, out);
}